// Round 1
// baseline (184.961 us; speedup 1.0000x reference)
//
#include <hip/hip_runtime.h>
#include <math.h>

// Analytic inverse of [[R, t],[0,0,0,1]] where R comes from a normalized quat:
// inv = [[R^T, -R^T t],[0,0,0,1]].
struct Inv {
    float i00, i01, i02, it0;
    float i10, i11, i12, it1;
    float i20, i21, i22, it2;
};

__device__ __forceinline__ Inv make_inv(const float* __restrict__ q,
                                        const float* __restrict__ t, int b) {
    float w = q[b * 4 + 0], x = q[b * 4 + 1], y = q[b * 4 + 2], z = q[b * 4 + 3];
    float inv_n = 1.0f / sqrtf(w * w + x * x + y * y + z * z);
    w *= inv_n; x *= inv_n; y *= inv_n; z *= inv_n;
    float R00 = 1.f - 2.f * y * y - 2.f * z * z;
    float R01 = 2.f * x * y - 2.f * z * w;
    float R02 = 2.f * x * z + 2.f * y * w;
    float R10 = 2.f * x * y + 2.f * z * w;
    float R11 = 1.f - 2.f * x * x - 2.f * z * z;
    float R12 = 2.f * y * z - 2.f * x * w;
    float R20 = 2.f * x * z - 2.f * y * w;
    float R21 = 2.f * y * z + 2.f * x * w;
    float R22 = 1.f - 2.f * x * x - 2.f * y * y;
    float t0 = t[b * 3 + 0], t1 = t[b * 3 + 1], t2 = t[b * 3 + 2];
    Inv v;
    v.i00 = R00; v.i01 = R10; v.i02 = R20; v.it0 = -(R00 * t0 + R10 * t1 + R20 * t2);
    v.i10 = R01; v.i11 = R11; v.i12 = R21; v.it1 = -(R01 * t0 + R11 * t1 + R21 * t2);
    v.i20 = R02; v.i21 = R12; v.i22 = R22; v.it2 = -(R02 * t0 + R12 * t1 + R22 * t2);
    return v;
}

__device__ __forceinline__ void xf(const Inv& M, float px, float py, float pz,
                                   float& ox, float& oy, float& oz) {
    ox = fmaf(M.i00, px, fmaf(M.i01, py, fmaf(M.i02, pz, M.it0)));
    oy = fmaf(M.i10, px, fmaf(M.i11, py, fmaf(M.i12, pz, M.it1)));
    oz = fmaf(M.i20, px, fmaf(M.i21, py, fmaf(M.i22, pz, M.it2)));
}

// Barrier that drains ONLY lgkmcnt (LDS), NOT vmcnt. HIP's __syncthreads emits
// a full `s_waitcnt vmcnt(0) lgkmcnt(0)` drain before s_barrier, which puts
// every global load AND store-ack on the per-iteration critical path. LDS
// cross-thread visibility only requires lgkmcnt(0); global loads/stores are
// thread-private here and may stay in flight across the barrier.
// Uniform control flow only (it is: loop trip count and guards are kernel args).
__device__ __forceinline__ void bar_lgkm() {
    asm volatile("s_waitcnt lgkmcnt(0)\n\ts_barrier" ::: "memory");
}

// Persistent pipelined version:
//  - grid = 64 x 32 = 2048 blocks = exactly 8 blocks/CU on 256 CUs (12 KB LDS,
//    ~60 VGPR): one generation, no tail, 4x fewer launch ramps.
//  - each block processes n_iters=4 chunks of 768 float4 (12 KB), strided by
//    stride_f4 so all accesses stay lane-contiguous float4.
//  - software pipeline: chunk i+1's 3 global loads are issued at the TOP of
//    iteration i and consumed (staged to LDS) only after compute + 1 barrier.
//    The compiler's exact vmcnt counting (loads issued before stores within
//    the iteration) leaves the 3 stores outstanding across barriers.
//  - 2 barriers/iter with a SINGLE buffer: the store-phase ds_reads
//    (smem[tid]-mapped) and the restage ds_writes use the identical
//    thread->slot mapping, so they are same-thread same-address WAR pairs —
//    LDS executes them in order per wave, no barrier needed between them.
// LDS compute-phase pattern unchanged: word-stride 12 between lanes -> 8
// consecutive lanes cover all 32 banks exactly once per ds_read_b128.
__global__ __launch_bounds__(256) void realign_fused_kernel(
        const float4* __restrict__ pcd,
        const float* __restrict__ T_mis,
        const float* __restrict__ q,
        const float* __restrict__ t,
        float* __restrict__ out_mat,
        float4* __restrict__ out_pcd,
        int f4_per_batch, int stride_f4, int n_iters) {
    __shared__ float4 smem[768];   // 12 KB
    const int b = blockIdx.y;
    const int tid = threadIdx.x;

    size_t base = (size_t)b * (size_t)f4_per_batch + (size_t)blockIdx.x * 768u;

    // Prologue: load + stage chunk 0 (b is wave-uniform -> make_inv scalarizes).
    float4 r0 = pcd[base + tid];
    float4 r1 = pcd[base + 256 + tid];
    float4 r2 = pcd[base + 512 + tid];

    const Inv M = make_inv(q, t, b);

    // Fused tmat: batch_T_pred[b] = inv_T[b] @ T_mis[b] (once per batch).
    if (blockIdx.x == 0 && tid < 16) {
        const int i = tid >> 2;
        const int j = tid & 3;
        const float* Tb = T_mis + b * 16;
        float val;
        if (i < 3) {
            float a0, a1, a2, it;
            if (i == 0)      { a0 = M.i00; a1 = M.i01; a2 = M.i02; it = M.it0; }
            else if (i == 1) { a0 = M.i10; a1 = M.i11; a2 = M.i12; it = M.it1; }
            else             { a0 = M.i20; a1 = M.i21; a2 = M.i22; it = M.it2; }
            val = fmaf(a0, Tb[0 * 4 + j],
                  fmaf(a1, Tb[1 * 4 + j],
                  fmaf(a2, Tb[2 * 4 + j],
                       it * Tb[3 * 4 + j])));
        } else {
            val = Tb[3 * 4 + j];
        }
        out_mat[b * 16 + tid] = val;
    }

    smem[tid]       = r0;
    smem[256 + tid] = r1;
    smem[512 + tid] = r2;
    bar_lgkm();

    for (int it = 0; it < n_iters; ++it) {
        // Prefetch chunk it+1 into registers (issued first -> oldest in the
        // vmcnt queue -> the restage ds_write below waits vmcnt(3), leaving
        // this iteration's 3 stores in flight).
        float4 n0{}, n1{}, n2{};
        const bool has_next = (it + 1 < n_iters);
        if (has_next) {
            const size_t nb = base + (size_t)stride_f4;
            n0 = pcd[nb + tid];
            n1 = pcd[nb + 256 + tid];
            n2 = pcd[nb + 512 + tid];
        }

        // Compute chunk `it` in place (each thread owns slots 3t..3t+2).
        float4 v0 = smem[3 * tid + 0];
        float4 v1 = smem[3 * tid + 1];
        float4 v2 = smem[3 * tid + 2];
        float4 o0, o1, o2;
        xf(M, v0.x, v0.y, v0.z, o0.x, o0.y, o0.z);
        xf(M, v0.w, v1.x, v1.y, o0.w, o1.x, o1.y);
        xf(M, v1.z, v1.w, v2.x, o1.z, o1.w, o2.x);
        xf(M, v2.y, v2.z, v2.w, o2.y, o2.z, o2.w);
        smem[3 * tid + 0] = o0;
        smem[3 * tid + 1] = o1;
        smem[3 * tid + 2] = o2;
        bar_lgkm();   // compute-writes visible to store-phase readers

        // Coalesced LDS -> global stores, then restage chunk it+1 into the
        // SAME slots (same thread, same address: in-order per wave, no
        // barrier needed between the read and the write).
        float4 s0 = smem[tid];
        float4 s1 = smem[256 + tid];
        float4 s2 = smem[512 + tid];
        out_pcd[base + tid]       = s0;
        out_pcd[base + 256 + tid] = s1;
        out_pcd[base + 512 + tid] = s2;
        if (has_next) {
            smem[tid]       = n0;
            smem[256 + tid] = n1;
            smem[512 + tid] = n2;
        }
        bar_lgkm();   // restage-writes visible to next iteration's compute

        base += (size_t)stride_f4;
    }
}

extern "C" void kernel_launch(void* const* d_in, const int* in_sizes, int n_in,
                              void* d_out, int out_size, void* d_ws, size_t ws_size,
                              hipStream_t stream) {
    const float* pcd   = (const float*)d_in[0];  // (B, N, 3)
    const float* T_mis = (const float*)d_in[1];  // (B, 4, 4)
    const float* q     = (const float*)d_in[2];  // (B, 4)
    const float* t     = (const float*)d_in[3];  // (B, 3)
    float* out = (float*)d_out;

    const int B = in_sizes[2] / 4;                            // 32
    const long long N = (long long)in_sizes[0] / (3LL * B);   // 262144
    const int f4_per_batch = (int)(3 * N / 4);                // 196608
    const int chunks = f4_per_batch / 768;                    // 256

    // 4 chunks per block -> 64 x 32 = 2048 blocks = exactly 8/CU, no tail.
    int iters = 4;
    if (chunks % 4 != 0) iters = (chunks % 2 == 0) ? 2 : 1;
    const int blocks_x = chunks / iters;                      // 64
    const int stride_f4 = blocks_x * 768;

    // Output layout: [0, B*16) = batch_T_pred; then pcd_new (float4-aligned).
    dim3 grid(blocks_x, B);
    realign_fused_kernel<<<grid, 256, 0, stream>>>(
        (const float4*)pcd, T_mis, q, t,
        out, (float4*)(out + B * 16), f4_per_batch, stride_f4, iters);
}

// Round 4
// 183.521 us; speedup vs baseline: 1.0079x; 1.0079x over previous
//
#include <hip/hip_runtime.h>
#include <math.h>

// Analytic inverse of [[R, t],[0,0,0,1]] where R comes from a normalized quat:
// inv = [[R^T, -R^T t],[0,0,0,1]].
struct Inv {
    float i00, i01, i02, it0;
    float i10, i11, i12, it1;
    float i20, i21, i22, it2;
};

__device__ __forceinline__ Inv make_inv(const float* __restrict__ q,
                                        const float* __restrict__ t, int b) {
    float w = q[b * 4 + 0], x = q[b * 4 + 1], y = q[b * 4 + 2], z = q[b * 4 + 3];
    float inv_n = 1.0f / sqrtf(w * w + x * x + y * y + z * z);
    w *= inv_n; x *= inv_n; y *= inv_n; z *= inv_n;
    float R00 = 1.f - 2.f * y * y - 2.f * z * z;
    float R01 = 2.f * x * y - 2.f * z * w;
    float R02 = 2.f * x * z + 2.f * y * w;
    float R10 = 2.f * x * y + 2.f * z * w;
    float R11 = 1.f - 2.f * x * x - 2.f * z * z;
    float R12 = 2.f * y * z - 2.f * x * w;
    float R20 = 2.f * x * z - 2.f * y * w;
    float R21 = 2.f * y * z + 2.f * x * w;
    float R22 = 1.f - 2.f * x * x - 2.f * y * y;
    float t0 = t[b * 3 + 0], t1 = t[b * 3 + 1], t2 = t[b * 3 + 2];
    Inv v;
    v.i00 = R00; v.i01 = R10; v.i02 = R20; v.it0 = -(R00 * t0 + R10 * t1 + R20 * t2);
    v.i10 = R01; v.i11 = R11; v.i12 = R21; v.it1 = -(R01 * t0 + R11 * t1 + R21 * t2);
    v.i20 = R02; v.i21 = R12; v.i22 = R22; v.it2 = -(R02 * t0 + R12 * t1 + R22 * t2);
    return v;
}

__device__ __forceinline__ void xf(const Inv& M, float px, float py, float pz,
                                   float& ox, float& oy, float& oz) {
    ox = fmaf(M.i00, px, fmaf(M.i01, py, fmaf(M.i02, pz, M.it0)));
    oy = fmaf(M.i10, px, fmaf(M.i11, py, fmaf(M.i12, pz, M.it1)));
    oz = fmaf(M.i20, px, fmaf(M.i21, py, fmaf(M.i22, pz, M.it2)));
}

// Barrier that drains ONLY lgkmcnt (LDS), NOT vmcnt (see Round-1 notes).
__device__ __forceinline__ void bar_lgkm() {
    asm volatile("s_waitcnt lgkmcnt(0)\n\ts_barrier" ::: "memory");
}

// Non-temporal float4 store: emits global_store_dwordx4 ... nt.
// THEORY UNDER TEST (3rd submission; rounds 2-3 died to broker/acquire
// failures, zero kernel data): the 96 MB output store-miss stream
// write-allocates in L3 (invisible to TCC FETCH/WRITE counters), adding a
// hidden ~96 MB HBM read + evicting the input from L3 between graph
// iterations. Round-0 (drain barriers, 8192 blocks) and Round-1 (counted
// vmcnt, persistent 2048 blocks) measured IDENTICAL 61 us at only 3.2 TB/s
// combined logical traffic with every per-CU issue resource <15% busy ->
// latency/scheduling is ruled out; a hidden-traffic throughput wall is the
// surviving theory. Output is written once, never re-read by the kernel:
// textbook non-temporal case.
using nat_f4 = __attribute__((ext_vector_type(4))) float;
__device__ __forceinline__ void store_nt(float4* p, const float4& v) {
    __builtin_nontemporal_store(*(const nat_f4*)&v, (nat_f4*)p);
}

// Persistent pipelined structure (unchanged from Round 1 for clean A/B):
//  - grid = 64 x 32 = 2048 blocks (persistent, 4 chunks of 768 float4 each);
//  - chunk i+1's 3 global loads issued at top of iter i, consumed after the
//    store phase (compiler emits counted vmcnt, stores stay in flight);
//  - 2 lgkm-only barriers per iteration, single 12 KB LDS buffer (store-phase
//    ds_reads and restage ds_writes are same-thread same-address WAR pairs,
//    in-order per wave, no barrier between them);
//  - LDS compute-phase stride 12 words/lane -> conflict-free ds_read_b128.
__global__ __launch_bounds__(256) void realign_fused_kernel(
        const float4* __restrict__ pcd,
        const float* __restrict__ T_mis,
        const float* __restrict__ q,
        const float* __restrict__ t,
        float* __restrict__ out_mat,
        float4* __restrict__ out_pcd,
        int f4_per_batch, int stride_f4, int n_iters) {
    __shared__ float4 smem[768];   // 12 KB
    const int b = blockIdx.y;
    const int tid = threadIdx.x;

    size_t base = (size_t)b * (size_t)f4_per_batch + (size_t)blockIdx.x * 768u;

    // Prologue: load + stage chunk 0 (b is wave-uniform -> make_inv scalarizes).
    float4 r0 = pcd[base + tid];
    float4 r1 = pcd[base + 256 + tid];
    float4 r2 = pcd[base + 512 + tid];

    const Inv M = make_inv(q, t, b);

    // Fused tmat: batch_T_pred[b] = inv_T[b] @ T_mis[b] (once per batch).
    if (blockIdx.x == 0 && tid < 16) {
        const int i = tid >> 2;
        const int j = tid & 3;
        const float* Tb = T_mis + b * 16;
        float val;
        if (i < 3) {
            float a0, a1, a2, it;
            if (i == 0)      { a0 = M.i00; a1 = M.i01; a2 = M.i02; it = M.it0; }
            else if (i == 1) { a0 = M.i10; a1 = M.i11; a2 = M.i12; it = M.it1; }
            else             { a0 = M.i20; a1 = M.i21; a2 = M.i22; it = M.it2; }
            val = fmaf(a0, Tb[0 * 4 + j],
                  fmaf(a1, Tb[1 * 4 + j],
                  fmaf(a2, Tb[2 * 4 + j],
                       it * Tb[3 * 4 + j])));
        } else {
            val = Tb[3 * 4 + j];
        }
        out_mat[b * 16 + tid] = val;
    }

    smem[tid]       = r0;
    smem[256 + tid] = r1;
    smem[512 + tid] = r2;
    bar_lgkm();

    for (int it = 0; it < n_iters; ++it) {
        // Prefetch chunk it+1 into registers.
        float4 n0{}, n1{}, n2{};
        const bool has_next = (it + 1 < n_iters);
        if (has_next) {
            const size_t nb = base + (size_t)stride_f4;
            n0 = pcd[nb + tid];
            n1 = pcd[nb + 256 + tid];
            n2 = pcd[nb + 512 + tid];
        }

        // Compute chunk `it` in place (each thread owns slots 3t..3t+2).
        float4 v0 = smem[3 * tid + 0];
        float4 v1 = smem[3 * tid + 1];
        float4 v2 = smem[3 * tid + 2];
        float4 o0, o1, o2;
        xf(M, v0.x, v0.y, v0.z, o0.x, o0.y, o0.z);
        xf(M, v0.w, v1.x, v1.y, o0.w, o1.x, o1.y);
        xf(M, v1.z, v1.w, v2.x, o1.z, o1.w, o2.x);
        xf(M, v2.y, v2.z, v2.w, o2.y, o2.z, o2.w);
        smem[3 * tid + 0] = o0;
        smem[3 * tid + 1] = o1;
        smem[3 * tid + 2] = o2;
        bar_lgkm();   // compute-writes visible to store-phase readers

        // Coalesced LDS -> global NON-TEMPORAL stores, then restage chunk
        // it+1 into the SAME slots (same thread, same address: in-order per
        // wave, no barrier needed between the read and the write).
        float4 s0 = smem[tid];
        float4 s1 = smem[256 + tid];
        float4 s2 = smem[512 + tid];
        store_nt(&out_pcd[base + tid],       s0);
        store_nt(&out_pcd[base + 256 + tid], s1);
        store_nt(&out_pcd[base + 512 + tid], s2);
        if (has_next) {
            smem[tid]       = n0;
            smem[256 + tid] = n1;
            smem[512 + tid] = n2;
        }
        bar_lgkm();   // restage-writes visible to next iteration's compute

        base += (size_t)stride_f4;
    }
}

extern "C" void kernel_launch(void* const* d_in, const int* in_sizes, int n_in,
                              void* d_out, int out_size, void* d_ws, size_t ws_size,
                              hipStream_t stream) {
    const float* pcd   = (const float*)d_in[0];  // (B, N, 3)
    const float* T_mis = (const float*)d_in[1];  // (B, 4, 4)
    const float* q     = (const float*)d_in[2];  // (B, 4)
    const float* t     = (const float*)d_in[3];  // (B, 3)
    float* out = (float*)d_out;

    const int B = in_sizes[2] / 4;                            // 32
    const long long N = (long long)in_sizes[0] / (3LL * B);   // 262144
    const int f4_per_batch = (int)(3 * N / 4);                // 196608
    const int chunks = f4_per_batch / 768;                    // 256

    // 4 chunks per block -> 64 x 32 = 2048 blocks, persistent, no tail.
    int iters = 4;
    if (chunks % 4 != 0) iters = (chunks % 2 == 0) ? 2 : 1;
    const int blocks_x = chunks / iters;                      // 64
    const int stride_f4 = blocks_x * 768;

    // Output layout: [0, B*16) = batch_T_pred; then pcd_new (float4-aligned).
    dim3 grid(blocks_x, B);
    realign_fused_kernel<<<grid, 256, 0, stream>>>(
        (const float4*)pcd, T_mis, q, t,
        out, (float4*)(out + B * 16), f4_per_batch, stride_f4, iters);
}